// Round 2
// baseline (179.119 us; speedup 1.0000x reference)
//
#include <hip/hip_runtime.h>
#include <stdint.h>

#define B_DET 8192
#define N_DIM 256
#define T_TRK 4096
#define Q_SLOT 64
#define EPSF 1e-9f

// Monotone map fp32 -> uint32 (ascending). No NaNs expected in this data.
__device__ __forceinline__ uint32_t f32_key(float f) {
    uint32_t u = __float_as_uint(f);
    return (u & 0x80000000u) ? ~u : (u | 0x80000000u);
}

// Kernel A: one block per detection b. Stage reprs[b] (1 KB) in LDS; 4 waves
// sweep the 64 memory slots of track t = tid[b]; per (b,q) dot product of
// length 256 via float4/lane + 64-lane butterfly; atomicMin packed (key, b).
__global__ __launch_bounds__(256)
void sim_argmin_kernel(const float* __restrict__ reprs,
                       const float* __restrict__ memory,
                       const int* __restrict__ track_idxs,
                       unsigned long long* __restrict__ best) {
    const int b = blockIdx.x;
    const int t = track_idxs[b];

    __shared__ float r_sh[N_DIM];
    r_sh[threadIdx.x] = reprs[(size_t)b * N_DIM + threadIdx.x];
    __syncthreads();

    const int wave = threadIdx.x >> 6;
    const int lane = threadIdx.x & 63;
    const float4 r = reinterpret_cast<const float4*>(r_sh)[lane];

    for (int q = wave; q < Q_SLOT; q += 4) {
        const float4* mrow = reinterpret_cast<const float4*>(
            memory + ((size_t)t * Q_SLOT + q) * N_DIM);
        float4 m = mrow[lane];
        float dot = m.x * r.x + m.y * r.y + m.z * r.z + m.w * r.w;
        #pragma unroll
        for (int off = 32; off >= 1; off >>= 1)
            dot += __shfl_xor(dot, off, 64);
        if (lane == 0) {
            unsigned long long packed =
                ((unsigned long long)f32_key(dot) << 32) | (uint32_t)b;
            atomicMin(best + (size_t)t * Q_SLOT + q, packed);
        }
    }
}

// Kernel B: one wave per (t,q) row. Untouched rows pass through; touched rows
// blend with reprs[chosen], renormalize (wave-reduced sum of squares), store.
__global__ __launch_bounds__(256)
void update_kernel(const float* __restrict__ reprs,
                   const float* __restrict__ memory,
                   const float* __restrict__ alpha,
                   const unsigned long long* __restrict__ best,
                   float* __restrict__ out) {
    const int row  = blockIdx.x * 4 + (threadIdx.x >> 6);   // t*Q + q
    const int lane = threadIdx.x & 63;
    const int q    = row & (Q_SLOT - 1);
    const size_t moff = (size_t)row * N_DIM;

    const float4 m = reinterpret_cast<const float4*>(memory + moff)[lane];
    const unsigned long long packed = best[row];

    if (packed == ~0ULL) {
        reinterpret_cast<float4*>(out + moff)[lane] = m;
        return;
    }

    const int bsel = (int)(uint32_t)packed;
    const float a  = alpha[q];
    const float na = 1.0f - a;
    const float4 r = reinterpret_cast<const float4*>(
        reprs + (size_t)bsel * N_DIM)[lane];

    float4 u;
    u.x = a * m.x + na * r.x;
    u.y = a * m.y + na * r.y;
    u.z = a * m.z + na * r.z;
    u.w = a * m.w + na * r.w;

    float ss = u.x * u.x + u.y * u.y + u.z * u.z + u.w * u.w;
    #pragma unroll
    for (int off = 32; off >= 1; off >>= 1)
        ss += __shfl_xor(ss, off, 64);

    const float scale = 1.0f / (sqrtf(ss) + EPSF);
    u.x *= scale; u.y *= scale; u.z *= scale; u.w *= scale;
    reinterpret_cast<float4*>(out + moff)[lane] = u;
}

extern "C" void kernel_launch(void* const* d_in, const int* in_sizes, int n_in,
                              void* d_out, int out_size, void* d_ws, size_t ws_size,
                              hipStream_t stream) {
    const float* reprs      = (const float*)d_in[0];
    const float* memory     = (const float*)d_in[1];
    const float* alpha      = (const float*)d_in[2];
    const int*   track_idxs = (const int*)d_in[3];   // harness converts int64 -> int32
    float*       out        = (float*)d_out;

    unsigned long long* best = (unsigned long long*)d_ws;
    const size_t best_bytes = (size_t)T_TRK * Q_SLOT * sizeof(unsigned long long); // 2 MiB

    // 0xFF.. == UINT64_MAX sentinel (= "no detection for this (t,q)")
    hipMemsetAsync(best, 0xFF, best_bytes, stream);

    sim_argmin_kernel<<<B_DET, 256, 0, stream>>>(reprs, memory, track_idxs, best);
    update_kernel<<<(T_TRK * Q_SLOT) / 4, 256, 0, stream>>>(reprs, memory, alpha, best, out);
}